// Round 9
// baseline (172.704 us; speedup 1.0000x reference)
//
#include <hip/hip_runtime.h>

#define SS 4096
#define DM 1024
#define PSTRIDE 1056  // 16*66 f32 per block partial

typedef __attribute__((ext_vector_type(4))) float f32x4;
typedef __attribute__((ext_vector_type(8))) __bf16 bf16x8;
typedef __attribute__((ext_vector_type(8))) unsigned short ushort8;
typedef __attribute__((ext_vector_type(4))) unsigned short ushort4v;
typedef __attribute__((ext_vector_type(2))) unsigned int uint2v;

#define NEGHUGE -3.0e38f
#define LOG2E 1.44269504f

__device__ __forceinline__ unsigned short f2b(float f) {
    unsigned u = __builtin_bit_cast(unsigned, f);
    u += 0x7fffu + ((u >> 16) & 1u);
    return (unsigned short)(u >> 16);
}

__device__ __forceinline__ f32x4 mfma16(ushort8 a, ushort8 b, f32x4 c) {
    return __builtin_amdgcn_mfma_f32_16x16x32_bf16(
        __builtin_bit_cast(bf16x8, a), __builtin_bit_cast(bf16x8, b), c, 0, 0, 0);
}

// ---------------- kernel 1: convert W (3x [64][1024] f32) -> wb bf16 [192][1024]
__global__ __launch_bounds__(256) void convw_kernel(
    const float* __restrict__ Wq, const float* __restrict__ Wk,
    const float* __restrict__ Wv, unsigned short* __restrict__ wb)
{
    int i = (blockIdx.x * 256 + threadIdx.x) * 4;
    const float* src;
    if (i < 65536) src = Wq + i;
    else if (i < 131072) src = Wk + (i - 65536);
    else src = Wv + (i - 131072);
    f32x4 v = *reinterpret_cast<const f32x4*>(src);
    ushort4v o;
    o[0] = f2b(v[0]); o[1] = f2b(v[1]); o[2] = f2b(v[2]); o[3] = f2b(v[3]);
    *reinterpret_cast<ushort4v*>(wb + i) = o;
}

// ---------------- kernel 2: QKV projection (unchanged from R8).
__global__ __launch_bounds__(256) void proj_kernel(
    const float* __restrict__ x, const unsigned short* __restrict__ wb,
    const float* __restrict__ bq, const float* __restrict__ bk, const float* __restrict__ bv,
    unsigned short* __restrict__ Qs, unsigned short* __restrict__ Kb,
    unsigned short* __restrict__ VT)
{
    __shared__ float comb[4 * 16 * 52];  // 13.3KB
    const int bid = blockIdx.x;
    const int m0 = (bid >> 2) * 16;
    const int fg = bid & 3;
    const int tid = threadIdx.x;
    const int w = tid >> 6, l = tid & 63;
    const int lc = l & 15;
    const int lg4 = l >> 4;
    const int lk = lg4 * 8;

    f32x4 acc[3] = {};
    const float* xrow = x + (m0 + lc) * DM;
    const unsigned short* wbase = wb + (fg * 48 + lc) * DM;
    const int kbase = w * 256;

    for (int kk = 0; kk < 256; kk += 32) {
        const int k0 = kbase + kk + lk;
        f32x4 u = *reinterpret_cast<const f32x4*>(xrow + k0);
        f32x4 v = *reinterpret_cast<const f32x4*>(xrow + k0 + 4);
        ushort8 a;
        a[0] = f2b(u[0]); a[1] = f2b(u[1]); a[2] = f2b(u[2]); a[3] = f2b(u[3]);
        a[4] = f2b(v[0]); a[5] = f2b(v[1]); a[6] = f2b(v[2]); a[7] = f2b(v[3]);
#pragma unroll
        for (int nf = 0; nf < 3; nf++) {
            ushort8 b = *reinterpret_cast<const ushort8*>(wbase + nf * 16 * DM + k0);
            acc[nf] = mfma16(a, b, acc[nf]);
        }
    }

#pragma unroll
    for (int nf = 0; nf < 3; nf++)
#pragma unroll
        for (int r = 0; r < 4; r++)
            comb[w * 832 + (lg4 * 4 + r) * 52 + nf * 16 + lc] = acc[nf][r];
    __syncthreads();

    for (int idx = tid; idx < 768; idx += 256) {
        int row = idx / 48, col = idx % 48;
        int off = row * 52 + col;
        float s = comb[off] + comb[832 + off] + comb[1664 + off] + comb[2496 + off];
        int grow = m0 + row;
        int gcol = fg * 48 + col;
        if (gcol < 64) {
            s += bq[gcol];
            Qs[grow * 64 + gcol] = f2b(s * 0.125f);  // fold 1/sqrt(64) into Q
        } else if (gcol < 128) {
            s += bk[gcol - 64];
            Kb[grow * 64 + gcol - 64] = f2b(s);
        } else {
            s += bv[gcol - 128];
            VT[(gcol - 128) * SS + grow] = f2b(s);
        }
    }
}

// ---------------- kernel 3: attention split-KV partials (unchanged from R8).
__global__ __launch_bounds__(256) void attn_part_kernel(
    const unsigned short* __restrict__ Qs, const unsigned short* __restrict__ Kb,
    const unsigned short* __restrict__ VT, float* __restrict__ part)
{
    __shared__ __align__(16) char plds[4 * 2304];  // 9.2KB: per-wave P bounce
    __shared__ float scomb[4][16 * 66];            // 16.9KB

    const int bid = blockIdx.x;
    const int g = 255 - (bid >> 2);   // big groups dispatch first
    const int c = bid & 3;
    const int q0 = g * 16;
    const int tid = threadIdx.x;
    const int w = tid >> 6, l = tid & 63;
    const int lc = l & 15;
    const int lg4 = l >> 4;
    const int lk = lg4 * 8;

    const int T = g / 4 + 1;
    const int W0 = c * 4 + w;

    ushort8 aq0 = *reinterpret_cast<const ushort8*>(Qs + (q0 + lc) * 64 + lk);
    ushort8 aq1 = *reinterpret_cast<const ushort8*>(Qs + (q0 + lc) * 64 + 32 + lk);

    float m4 = NEGHUGE, l4 = 0.f;
    f32x4 o[4] = {};

    char* myp = plds + w * 2304;

    for (int t = W0; t < T; t += 16) {
        const int kv0 = t * 64;
        f32x4 s[4] = {};
#pragma unroll
        for (int nf = 0; nf < 4; nf++) {
            const unsigned short* kr = Kb + (kv0 + nf * 16 + lc) * 64;
            ushort8 b0 = *reinterpret_cast<const ushort8*>(kr + lk);
            ushort8 b1 = *reinterpret_cast<const ushort8*>(kr + 32 + lk);
            s[nf] = mfma16(b0, aq0, s[nf]);   // A=K, B=Q
            s[nf] = mfma16(b1, aq1, s[nf]);
        }
        ushort8 av[2][4];
#pragma unroll
        for (int cc = 0; cc < 2; cc++)
#pragma unroll
            for (int df = 0; df < 4; df++)
                av[cc][df] = *reinterpret_cast<const ushort8*>(
                    VT + (df * 16 + lc) * SS + kv0 + cc * 32 + lk);

        if (kv0 + 63 > q0) {
#pragma unroll
            for (int nf = 0; nf < 4; nf++)
#pragma unroll
                for (int r = 0; r < 4; r++) {
                    int kvi = kv0 + nf * 16 + lg4 * 4 + r;
                    if (kvi > q0 + lc) s[nf][r] = NEGHUGE;
                }
        }
        float mx01 = fmaxf(fmaxf(s[0][0], s[0][1]), fmaxf(s[0][2], s[0][3]));
        float mx11 = fmaxf(fmaxf(s[1][0], s[1][1]), fmaxf(s[1][2], s[1][3]));
        float mx21 = fmaxf(fmaxf(s[2][0], s[2][1]), fmaxf(s[2][2], s[2][3]));
        float mx31 = fmaxf(fmaxf(s[3][0], s[3][1]), fmaxf(s[3][2], s[3][3]));
        float mx = fmaxf(fmaxf(mx01, mx11), fmaxf(mx21, mx31));
        mx = fmaxf(mx, __shfl_xor(mx, 16));
        mx = fmaxf(mx, __shfl_xor(mx, 32));
        float mn = fmaxf(m4, mx);
        float sc = exp2f((m4 - mn) * LOG2E);
        m4 = mn;
        float rs = 0.f;
#pragma unroll
        for (int nf = 0; nf < 4; nf++)
#pragma unroll
            for (int r = 0; r < 4; r++) {
                float p = exp2f((s[nf][r] - mn) * LOG2E);
                s[nf][r] = p;
                rs += p;
            }
        rs += __shfl_xor(rs, 16);
        rs += __shfl_xor(rs, 32);
        l4 = l4 * sc + rs;
#pragma unroll
        for (int df = 0; df < 4; df++) {
            o[df][0] *= sc; o[df][1] *= sc; o[df][2] *= sc; o[df][3] *= sc;
        }
#pragma unroll
        for (int nf = 0; nf < 4; nf++) {
            unsigned p01 = (unsigned)f2b(s[nf][0]) | ((unsigned)f2b(s[nf][1]) << 16);
            unsigned p23 = (unsigned)f2b(s[nf][2]) | ((unsigned)f2b(s[nf][3]) << 16);
            uint2v pk; pk[0] = p01; pk[1] = p23;
            *reinterpret_cast<uint2v*>(myp + lc * 144 + (nf * 8 + lg4 * 2) * 4) = pk;
        }
        asm volatile("s_waitcnt lgkmcnt(0)" ::: "memory");
        __builtin_amdgcn_sched_barrier(0);
#pragma unroll
        for (int cc = 0; cc < 2; cc++) {
            int S = 16 * cc + 4 * lg4;
            ushort8 pb = *reinterpret_cast<const ushort8*>(myp + lc * 144 + S * 4);
#pragma unroll
            for (int df = 0; df < 4; df++)
                o[df] = mfma16(av[cc][df], pb, o[df]);   // A=V^T, B=P
        }
    }

#pragma unroll
    for (int df = 0; df < 4; df++)
#pragma unroll
        for (int r = 0; r < 4; r++)
            scomb[w][lc * 66 + df * 16 + lg4 * 4 + r] = o[df][r];
    if (lg4 == 0) {
        scomb[w][lc * 66 + 64] = m4;
        scomb[w][lc * 66 + 65] = l4;
    }
    __syncthreads();

    float* pp = part + bid * PSTRIDE;
    for (int idx = tid; idx < 1024; idx += 256) {
        int row = idx >> 6, col = idx & 63;
        float M = fmaxf(fmaxf(scomb[0][row * 66 + 64], scomb[1][row * 66 + 64]),
                        fmaxf(scomb[2][row * 66 + 64], scomb[3][row * 66 + 64]));
        float val = 0.f, den = 0.f;
#pragma unroll
        for (int ww = 0; ww < 4; ww++) {
            float f = exp2f((scomb[ww][row * 66 + 64] - M) * LOG2E);
            val += scomb[ww][row * 66 + col] * f;
            den += scomb[ww][row * 66 + 65] * f;
        }
        pp[row * 66 + col] = val;
        if (col == 0) {
            pp[row * 66 + 64] = M;
            pp[row * 66 + 65] = den;
        }
    }
}

// ---------------- kernel 4: combine the 4 KV-chunk partials per group.
__global__ __launch_bounds__(256) void attn_comb_kernel(
    const float* __restrict__ part, float* __restrict__ out)
{
    const int b = blockIdx.x;
    const int g = 255 - b;
    const int q0 = g * 16;
    const float* p0 = part + (b * 4) * PSTRIDE;
    for (int idx = threadIdx.x; idx < 1024; idx += 256) {
        int row = idx >> 6, col = idx & 63;
        float M = NEGHUGE;
#pragma unroll
        for (int cc = 0; cc < 4; cc++)
            M = fmaxf(M, p0[cc * PSTRIDE + row * 66 + 64]);
        float val = 0.f, den = 0.f;
#pragma unroll
        for (int cc = 0; cc < 4; cc++) {
            float f = exp2f((p0[cc * PSTRIDE + row * 66 + 64] - M) * LOG2E);
            val += p0[cc * PSTRIDE + row * 66 + col] * f;
            den += p0[cc * PSTRIDE + row * 66 + 65] * f;
        }
        out[(q0 + row) * 64 + col] = val / den;
    }
}

extern "C" void kernel_launch(void* const* d_in, const int* in_sizes, int n_in,
                              void* d_out, int out_size, void* d_ws, size_t ws_size,
                              hipStream_t stream) {
    const float* x  = (const float*)d_in[0];
    const float* Wq = (const float*)d_in[1];
    const float* bq = (const float*)d_in[2];
    const float* Wk = (const float*)d_in[3];
    const float* bk = (const float*)d_in[4];
    const float* Wv = (const float*)d_in[5];
    const float* bv = (const float*)d_in[6];
    float* out = (float*)d_out;

    char* ws = (char*)d_ws;
    unsigned short* wb = (unsigned short*)ws;               // 393216 B
    unsigned short* Qs = (unsigned short*)(ws + 393216);    // 524288 B
    unsigned short* Kb = (unsigned short*)(ws + 917504);    // 524288 B
    unsigned short* VT = (unsigned short*)(ws + 1441792);   // 524288 B
    float* part = (float*)(ws + 1966080);                   // 1024*1056*4 B

    convw_kernel<<<dim3(192), dim3(256), 0, stream>>>(Wq, Wk, Wv, wb);
    // MEASUREMENT PROBE: proj is idempotent (pure function of x, wb -> Qs/Kb/VT).
    // Launch it 6x; dur_us delta vs R8 (59.6us) = 5 x (proj + per-node gap).
    for (int rep = 0; rep < 6; rep++)
        proj_kernel<<<dim3(1024), dim3(256), 0, stream>>>(x, wb, bq, bk, bv, Qs, Kb, VT);
    attn_part_kernel<<<dim3(1024), dim3(256), 0, stream>>>(Qs, Kb, VT, part);
    attn_comb_kernel<<<dim3(256), dim3(256), 0, stream>>>(part, out);
}

// Round 10
// 95.587 us; speedup vs baseline: 1.8068x; 1.8068x over previous
//
#include <hip/hip_runtime.h>

#define SS 4096
#define DM 1024
#define PSTRIDE 1056  // 16*66 f32 per block partial
#define AREPS 3       // attn_part internal repeats (measurement probe)

typedef __attribute__((ext_vector_type(4))) float f32x4;
typedef __attribute__((ext_vector_type(8))) __bf16 bf16x8;
typedef __attribute__((ext_vector_type(8))) unsigned short ushort8;
typedef __attribute__((ext_vector_type(4))) unsigned short ushort4v;
typedef __attribute__((ext_vector_type(2))) unsigned int uint2v;

#define NEGHUGE -3.0e38f
#define LOG2E 1.44269504f

__device__ __forceinline__ unsigned short f2b(float f) {
    unsigned u = __builtin_bit_cast(unsigned, f);
    u += 0x7fffu + ((u >> 16) & 1u);
    return (unsigned short)(u >> 16);
}

__device__ __forceinline__ f32x4 mfma16(ushort8 a, ushort8 b, f32x4 c) {
    return __builtin_amdgcn_mfma_f32_16x16x32_bf16(
        __builtin_bit_cast(bf16x8, a), __builtin_bit_cast(bf16x8, b), c, 0, 0, 0);
}

// ---------------- kernel 1: convert W (3x [64][1024] f32) -> wb bf16 [192][1024]
__global__ __launch_bounds__(256) void convw_kernel(
    const float* __restrict__ Wq, const float* __restrict__ Wk,
    const float* __restrict__ Wv, unsigned short* __restrict__ wb)
{
    int i = (blockIdx.x * 256 + threadIdx.x) * 4;
    const float* src;
    if (i < 65536) src = Wq + i;
    else if (i < 131072) src = Wk + (i - 65536);
    else src = Wv + (i - 131072);
    f32x4 v = *reinterpret_cast<const f32x4*>(src);
    ushort4v o;
    o[0] = f2b(v[0]); o[1] = f2b(v[1]); o[2] = f2b(v[2]); o[3] = f2b(v[3]);
    *reinterpret_cast<ushort4v*>(wb + i) = o;
}

// ---------------- kernel 2: QKV projection, XCD-colocated fg split.
// grid 1024: m0 = (bid&255)*16, fg = bid>>8  ->  the 4 blocks sharing one
// m-tile's x rows are bids {m, m+256, m+512, m+768} == same XCD (mod 8):
// x is HBM-fetched once and L2-resident per XCD (2MB/XCD).  [R8 had the
// decomposition swapped -> 4x HBM refetch of x across XCDs.]
__global__ __launch_bounds__(256) void proj_kernel(
    const float* __restrict__ x, const unsigned short* __restrict__ wb,
    const float* __restrict__ bq, const float* __restrict__ bk, const float* __restrict__ bv,
    unsigned short* __restrict__ Qs, unsigned short* __restrict__ Kb,
    unsigned short* __restrict__ VT)
{
    __shared__ float comb[4 * 16 * 52];  // 13.3KB
    const int bid = blockIdx.x;
    const int m0 = (bid & 255) * 16;
    const int fg = bid >> 8;
    const int tid = threadIdx.x;
    const int w = tid >> 6, l = tid & 63;
    const int lc = l & 15;
    const int lg4 = l >> 4;
    const int lk = lg4 * 8;

    f32x4 acc[3] = {};
    const float* xrow = x + (m0 + lc) * DM;
    const unsigned short* wbase = wb + (fg * 48 + lc) * DM;
    const int kbase = w * 256;

    for (int kk = 0; kk < 256; kk += 32) {
        const int k0 = kbase + kk + lk;
        f32x4 u = *reinterpret_cast<const f32x4*>(xrow + k0);
        f32x4 v = *reinterpret_cast<const f32x4*>(xrow + k0 + 4);
        ushort8 a;
        a[0] = f2b(u[0]); a[1] = f2b(u[1]); a[2] = f2b(u[2]); a[3] = f2b(u[3]);
        a[4] = f2b(v[0]); a[5] = f2b(v[1]); a[6] = f2b(v[2]); a[7] = f2b(v[3]);
#pragma unroll
        for (int nf = 0; nf < 3; nf++) {
            ushort8 b = *reinterpret_cast<const ushort8*>(wbase + nf * 16 * DM + k0);
            acc[nf] = mfma16(a, b, acc[nf]);
        }
    }

#pragma unroll
    for (int nf = 0; nf < 3; nf++)
#pragma unroll
        for (int r = 0; r < 4; r++)
            comb[w * 832 + (lg4 * 4 + r) * 52 + nf * 16 + lc] = acc[nf][r];
    __syncthreads();

    for (int idx = tid; idx < 768; idx += 256) {
        int row = idx / 48, col = idx % 48;
        int off = row * 52 + col;
        float s = comb[off] + comb[832 + off] + comb[1664 + off] + comb[2496 + off];
        int grow = m0 + row;
        int gcol = fg * 48 + col;
        if (gcol < 64) {
            s += bq[gcol];
            Qs[grow * 64 + gcol] = f2b(s * 0.125f);  // fold 1/sqrt(64) into Q
        } else if (gcol < 128) {
            s += bk[gcol - 64];
            Kb[grow * 64 + gcol - 64] = f2b(s);
        } else {
            s += bv[gcol - 128];
            VT[(gcol - 128) * SS + grow] = f2b(s);
        }
    }
}

// ---------------- kernel 3: attention split-KV partials (R8 body), internally
// repeated AREPS x as a MEASUREMENT PROBE: idempotent (same inputs -> same
// part), pushes this dispatch above the 41us harness fills so its rocprof
// counters surface in top-5. True per-pass cost = dispatch_dur / AREPS.
__global__ __launch_bounds__(256) void attn_part_kernel(
    const unsigned short* __restrict__ Qs, const unsigned short* __restrict__ Kb,
    const unsigned short* __restrict__ VT, float* __restrict__ part)
{
    __shared__ __align__(16) char plds[4 * 2304];  // 9.2KB: per-wave P bounce
    __shared__ float scomb[4][16 * 66];            // 16.9KB

    const int bid = blockIdx.x;
    const int g = 255 - (bid >> 2);   // big groups dispatch first
    const int c = bid & 3;
    const int q0 = g * 16;
    const int tid = threadIdx.x;
    const int w = tid >> 6, l = tid & 63;
    const int lc = l & 15;
    const int lg4 = l >> 4;
    const int lk = lg4 * 8;

    const int T = g / 4 + 1;
    const int W0 = c * 4 + w;

    ushort8 aq0 = *reinterpret_cast<const ushort8*>(Qs + (q0 + lc) * 64 + lk);
    ushort8 aq1 = *reinterpret_cast<const ushort8*>(Qs + (q0 + lc) * 64 + 32 + lk);

    char* myp = plds + w * 2304;

    for (int rep = 0; rep < AREPS; ++rep) {
        float m4 = NEGHUGE, l4 = 0.f;
        f32x4 o[4] = {};

        for (int t = W0; t < T; t += 16) {
            const int kv0 = t * 64;
            f32x4 s[4] = {};
#pragma unroll
            for (int nf = 0; nf < 4; nf++) {
                const unsigned short* kr = Kb + (kv0 + nf * 16 + lc) * 64;
                ushort8 b0 = *reinterpret_cast<const ushort8*>(kr + lk);
                ushort8 b1 = *reinterpret_cast<const ushort8*>(kr + 32 + lk);
                s[nf] = mfma16(b0, aq0, s[nf]);   // A=K, B=Q
                s[nf] = mfma16(b1, aq1, s[nf]);
            }
            ushort8 av[2][4];
#pragma unroll
            for (int cc = 0; cc < 2; cc++)
#pragma unroll
                for (int df = 0; df < 4; df++)
                    av[cc][df] = *reinterpret_cast<const ushort8*>(
                        VT + (df * 16 + lc) * SS + kv0 + cc * 32 + lk);

            if (kv0 + 63 > q0) {
#pragma unroll
                for (int nf = 0; nf < 4; nf++)
#pragma unroll
                    for (int r = 0; r < 4; r++) {
                        int kvi = kv0 + nf * 16 + lg4 * 4 + r;
                        if (kvi > q0 + lc) s[nf][r] = NEGHUGE;
                    }
            }
            float mx01 = fmaxf(fmaxf(s[0][0], s[0][1]), fmaxf(s[0][2], s[0][3]));
            float mx11 = fmaxf(fmaxf(s[1][0], s[1][1]), fmaxf(s[1][2], s[1][3]));
            float mx21 = fmaxf(fmaxf(s[2][0], s[2][1]), fmaxf(s[2][2], s[2][3]));
            float mx31 = fmaxf(fmaxf(s[3][0], s[3][1]), fmaxf(s[3][2], s[3][3]));
            float mx = fmaxf(fmaxf(mx01, mx11), fmaxf(mx21, mx31));
            mx = fmaxf(mx, __shfl_xor(mx, 16));
            mx = fmaxf(mx, __shfl_xor(mx, 32));
            float mn = fmaxf(m4, mx);
            float sc = exp2f((m4 - mn) * LOG2E);
            m4 = mn;
            float rs = 0.f;
#pragma unroll
            for (int nf = 0; nf < 4; nf++)
#pragma unroll
                for (int r = 0; r < 4; r++) {
                    float p = exp2f((s[nf][r] - mn) * LOG2E);
                    s[nf][r] = p;
                    rs += p;
                }
            rs += __shfl_xor(rs, 16);
            rs += __shfl_xor(rs, 32);
            l4 = l4 * sc + rs;
#pragma unroll
            for (int df = 0; df < 4; df++) {
                o[df][0] *= sc; o[df][1] *= sc; o[df][2] *= sc; o[df][3] *= sc;
            }
#pragma unroll
            for (int nf = 0; nf < 4; nf++) {
                unsigned p01 = (unsigned)f2b(s[nf][0]) | ((unsigned)f2b(s[nf][1]) << 16);
                unsigned p23 = (unsigned)f2b(s[nf][2]) | ((unsigned)f2b(s[nf][3]) << 16);
                uint2v pk; pk[0] = p01; pk[1] = p23;
                *reinterpret_cast<uint2v*>(myp + lc * 144 + (nf * 8 + lg4 * 2) * 4) = pk;
            }
            asm volatile("s_waitcnt lgkmcnt(0)" ::: "memory");
            __builtin_amdgcn_sched_barrier(0);
#pragma unroll
            for (int cc = 0; cc < 2; cc++) {
                int S = 16 * cc + 4 * lg4;
                ushort8 pb = *reinterpret_cast<const ushort8*>(myp + lc * 144 + S * 4);
#pragma unroll
                for (int df = 0; df < 4; df++)
                    o[df] = mfma16(av[cc][df], pb, o[df]);   // A=V^T, B=P
            }
        }

#pragma unroll
        for (int df = 0; df < 4; df++)
#pragma unroll
            for (int r = 0; r < 4; r++)
                scomb[w][lc * 66 + df * 16 + lg4 * 4 + r] = o[df][r];
        if (lg4 == 0) {
            scomb[w][lc * 66 + 64] = m4;
            scomb[w][lc * 66 + 65] = l4;
        }
        __syncthreads();

        float* pp = part + bid * PSTRIDE;
        for (int idx = tid; idx < 1024; idx += 256) {
            int row = idx >> 6, col = idx & 63;
            float M = fmaxf(fmaxf(scomb[0][row * 66 + 64], scomb[1][row * 66 + 64]),
                            fmaxf(scomb[2][row * 66 + 64], scomb[3][row * 66 + 64]));
            float val = 0.f, den = 0.f;
#pragma unroll
            for (int ww = 0; ww < 4; ww++) {
                float f = exp2f((scomb[ww][row * 66 + 64] - M) * LOG2E);
                val += scomb[ww][row * 66 + col] * f;
                den += scomb[ww][row * 66 + 65] * f;
            }
            pp[row * 66 + col] = val;
            if (col == 0) {
                pp[row * 66 + 64] = M;
                pp[row * 66 + 65] = den;
            }
        }
        __syncthreads();   // scomb reused next rep
    }
}

// ---------------- kernel 4: combine the 4 KV-chunk partials per group.
__global__ __launch_bounds__(256) void attn_comb_kernel(
    const float* __restrict__ part, float* __restrict__ out)
{
    const int b = blockIdx.x;
    const int g = 255 - b;
    const int q0 = g * 16;
    const float* p0 = part + (b * 4) * PSTRIDE;
    for (int idx = threadIdx.x; idx < 1024; idx += 256) {
        int row = idx >> 6, col = idx & 63;
        float M = NEGHUGE;
#pragma unroll
        for (int cc = 0; cc < 4; cc++)
            M = fmaxf(M, p0[cc * PSTRIDE + row * 66 + 64]);
        float val = 0.f, den = 0.f;
#pragma unroll
        for (int cc = 0; cc < 4; cc++) {
            float f = exp2f((p0[cc * PSTRIDE + row * 66 + 64] - M) * LOG2E);
            val += p0[cc * PSTRIDE + row * 66 + col] * f;
            den += p0[cc * PSTRIDE + row * 66 + 65] * f;
        }
        out[(q0 + row) * 64 + col] = val / den;
    }
}

extern "C" void kernel_launch(void* const* d_in, const int* in_sizes, int n_in,
                              void* d_out, int out_size, void* d_ws, size_t ws_size,
                              hipStream_t stream) {
    const float* x  = (const float*)d_in[0];
    const float* Wq = (const float*)d_in[1];
    const float* bq = (const float*)d_in[2];
    const float* Wk = (const float*)d_in[3];
    const float* bk = (const float*)d_in[4];
    const float* Wv = (const float*)d_in[5];
    const float* bv = (const float*)d_in[6];
    float* out = (float*)d_out;

    char* ws = (char*)d_ws;
    unsigned short* wb = (unsigned short*)ws;               // 393216 B
    unsigned short* Qs = (unsigned short*)(ws + 393216);    // 524288 B
    unsigned short* Kb = (unsigned short*)(ws + 917504);    // 524288 B
    unsigned short* VT = (unsigned short*)(ws + 1441792);   // 524288 B
    float* part = (float*)(ws + 1966080);                   // 1024*1056*4 B

    convw_kernel<<<dim3(192), dim3(256), 0, stream>>>(Wq, Wk, Wv, wb);
    proj_kernel<<<dim3(1024), dim3(256), 0, stream>>>(x, wb, bq, bk, bv, Qs, Kb, VT);
    attn_part_kernel<<<dim3(1024), dim3(256), 0, stream>>>(Qs, Kb, VT, part);
    attn_comb_kernel<<<dim3(256), dim3(256), 0, stream>>>(part, out);
}